// Round 4
// baseline (75.086 us; speedup 1.0000x reference)
//
#include <hip/hip_runtime.h>
#include <hip/hip_cooperative_groups.h>

namespace cg = cooperative_groups;

// WKV power kernel, R4: single cooperative kernel, 3 phases + 2 grid syncs.
//  P1 (block=chunk, thread=dim): coalesced k/v load, kx/vx kept in registers,
//      per-chunk affine carries -> ws.
//  P2 (block=dim, thread=chunk): Kogge-Stone scan of 256 chunk carries.
//  P3 (= P1 mapping): seed with prefix, reuse register kx/vx, fused output.

constexpr int T = 1024;
constexpr int D = 256;
constexpr int L = 4;               // rows per chunk
constexpr int NC = T / L;          // 256 chunks

__global__ __launch_bounds__(256) void wkv_coop(
    const float* __restrict__ k, const float* __restrict__ v,
    const float* __restrict__ time_first, const float* __restrict__ time_decay,
    float* __restrict__ bk_ws, float* __restrict__ bv_ws,
    float* __restrict__ pk_ws, float* __restrict__ pv_ws,
    float* __restrict__ out)
{
    __shared__ float wbk[4], wbv[4];
    cg::grid_group grid = cg::this_grid();

    const int c = blockIdx.x;      // chunk (phases 1 & 3)
    const int d = threadIdx.x;     // dim   (phases 1 & 3)
    const int base = c * L;

    const float td = time_decay[d];
    const float wd = __expf(td);

    // ---- Phase 1: local recurrence seeded 0; kx/vx stay in registers ----
    float kx[L], vx[L];
    float bk = 0.f, bv = 0.f;
#pragma unroll
    for (int j = 0; j < L; ++j) {
        const float kk = k[(base + j) * D + d];   // coalesced
        const float vv = v[(base + j) * D + d];   // coalesced
        const float e  = __expf(kk);
        kx[j] = e;
        vx[j] = vv * e;
        bk = wd * (kx[j] + bk);    // s <- w*(x + s)
        bv = wd * (vx[j] + bv);
    }
    bk_ws[c * D + d] = bk;         // coalesced
    bv_ws[c * D + d] = bv;

    grid.sync();

    // ---- Phase 2: block = dim b, thread = chunk t ----
    {
        const int b    = blockIdx.x;
        const int t    = threadIdx.x;
        const int lane = t & 63;
        const int wv   = t >> 6;
        const float td2 = time_decay[b];

        float sbk = bk_ws[t * D + b];   // strided, 512 KB total, L2-resident
        float sbv = bv_ws[t * D + b];

        // Kogge-Stone inclusive scan; uniform chunk multiplier m4 = w^L,
        // o-span factor = m4^o (f = f*f each step).
        float f = __expf(td2 * (float)L);
#pragma unroll
        for (int o = 1; o < 64; o <<= 1) {
            const float pk_ = __shfl_up(sbk, o);
            const float pv_ = __shfl_up(sbv, o);
            if (lane >= o) {
                sbk = fmaf(f, pk_, sbk);
                sbv = fmaf(f, pv_, sbv);
            }
            f = f * f;
        }

        if (lane == 63) { wbk[wv] = sbk; wbv[wv] = sbv; }
        __syncthreads();
        const float m256 = __expf(td2 * (float)(L * 64));
        float Pk = 0.f, Pv = 0.f;
        for (int u = 0; u < wv; ++u) {
            Pk = fmaf(m256, Pk, wbk[u]);
            Pv = fmaf(m256, Pv, wbv[u]);
        }

        float ek = __shfl_up(sbk, 1);
        float ev = __shfl_up(sbv, 1);
        if (lane == 0) { ek = 0.f; ev = 0.f; }
        const float mlane = __expf(td2 * (float)(L * lane));
        pk_ws[t * D + b] = fmaf(mlane, Pk, ek);   // state entering chunk t
        pv_ws[t * D + b] = fmaf(mlane, Pv, ev);
    }

    grid.sync();

    // ---- Phase 3: seed with prefix; reuse register kx/vx; fused output ----
    const float tf = __expf(time_first[d]);
    float sk = pk_ws[c * D + d];   // coalesced
    float sv = pv_ws[c * D + d];
#pragma unroll
    for (int j = 0; j < L; ++j) {
        sk = wd * (kx[j] + sk);                 // kxr
        sv = wd * (vx[j] + sv);                 // vxr
        const float num = fmaf(vx[j], tf, sk);  // vx*tf + kxr (faithful swap)
        const float den = fmaf(kx[j], tf, sv);  // kx*tf + vxr
        out[(base + j) * D + d] = num * __builtin_amdgcn_rcpf(den);  // coalesced
    }
}

extern "C" void kernel_launch(void* const* d_in, const int* in_sizes, int n_in,
                              void* d_out, int out_size, void* d_ws, size_t ws_size,
                              hipStream_t stream) {
    const float* k  = (const float*)d_in[0];
    const float* v  = (const float*)d_in[1];
    const float* tf = (const float*)d_in[2];
    const float* td = (const float*)d_in[3];
    float* out = (float*)d_out;

    float* ws = (float*)d_ws;
    float* bk_ws = ws;                 // [NC][D]
    float* bv_ws = ws + NC * D;
    float* pk_ws = ws + 2 * NC * D;
    float* pv_ws = ws + 3 * NC * D;

    void* args[] = { (void*)&k, (void*)&v, (void*)&tf, (void*)&td,
                     (void*)&bk_ws, (void*)&bv_ws, (void*)&pk_ws, (void*)&pv_ws,
                     (void*)&out };
    hipLaunchCooperativeKernel((const void*)wkv_coop,
                               dim3(NC), dim3(D), args, 0, stream);
}

// Round 5
// 11.552 us; speedup vs baseline: 6.4998x; 6.4998x over previous
//
#include <hip/hip_runtime.h>

// WKV power kernel, R5: single dispatch, 256 blocks x 1 wave (64 threads).
// Block = one dim (block-uniform -> scalar loads of decay/first).
// Lane = chunk of L=16 rows. Pure in-wave Kogge-Stone affine scan:
// no LDS, no __syncthreads, no cross-wave combine -> minimal critical path.

constexpr int T = 1024;
constexpr int D = 256;
constexpr int L = 16;              // rows per lane (64 lanes * 16 = 1024)

__global__ __launch_bounds__(64) void wkv_scan_kernel(
    const float* __restrict__ k, const float* __restrict__ v,
    const float* __restrict__ time_first, const float* __restrict__ time_decay,
    float* __restrict__ out)
{
    const int d    = blockIdx.x;       // dim (uniform across the wave)
    const int lane = threadIdx.x;      // chunk index 0..63

    const float td = time_decay[d];    // scalar (s_load: d is block-uniform)
    const float wd = __expf(td);       // per-row decay
    const float tf = __expf(time_first[d]);

    const int base = lane * L;

    // ---- Phase 1: local recurrence seeded 0; kx/vx live in registers ----
    float kx[L], vx[L];
    float bk = 0.f, bv = 0.f;
#pragma unroll
    for (int j = 0; j < L; ++j) {
        const float kk = k[(base + j) * D + d];
        const float vv = v[(base + j) * D + d];
        const float e  = __expf(kk);
        kx[j] = e;
        vx[j] = vv * e;
        bk = wd * (e + bk);            // s <- w*(x + s)
        bv = wd * (vx[j] + bv);
    }

    // ---- Phase 2: Kogge-Stone inclusive scan across 64 lanes.
    // Chunk multiplier uniform (m = w^L); o-span factor f = m^o, f *= f.
    float f = __expf(td * (float)L);
#pragma unroll
    for (int o = 1; o < 64; o <<= 1) {
        const float pk = __shfl_up(bk, o);
        const float pv = __shfl_up(bv, o);
        if (lane >= o) {
            bk = fmaf(f, pk, bk);
            bv = fmaf(f, pv, bv);
        }
        f = f * f;
    }

    // Exclusive prefix: state entering this lane's chunk.
    float sk = __shfl_up(bk, 1);
    float sv = __shfl_up(bv, 1);
    if (lane == 0) { sk = 0.f; sv = 0.f; }

    // ---- Phase 3: re-run local recurrence seeded with prefix; fused output ----
#pragma unroll
    for (int j = 0; j < L; ++j) {
        sk = wd * (kx[j] + sk);                 // = kxr[i]
        sv = wd * (vx[j] + sv);                 // = vxr[i]
        const float num = fmaf(vx[j], tf, sk);  // vx*tf + kxr (faithful swap)
        const float den = fmaf(kx[j], tf, sv);  // kx*tf + vxr
        out[(base + j) * D + d] = num * __builtin_amdgcn_rcpf(den);
    }
}

extern "C" void kernel_launch(void* const* d_in, const int* in_sizes, int n_in,
                              void* d_out, int out_size, void* d_ws, size_t ws_size,
                              hipStream_t stream) {
    const float* k  = (const float*)d_in[0];
    const float* v  = (const float*)d_in[1];
    const float* tf = (const float*)d_in[2];
    const float* td = (const float*)d_in[3];
    float* out = (float*)d_out;

    dim3 grid(D);                  // 256 blocks: one dim each -> all 256 CUs
    dim3 block(64);                // 1 wave per block
    wkv_scan_kernel<<<grid, block, 0, stream>>>(k, v, tf, td, out);
}